// Round 15
// baseline (469.374 us; speedup 1.0000x reference)
//
#include <hip/hip_runtime.h>
#include <hip/hip_bf16.h>
#include <math.h>

#define B_   4
#define S_   1024
#define HID_ 1024
#define H_   16
#define DH_  64
#define FF_  4096
#define MREL_ 256

typedef __attribute__((ext_vector_type(4))) float f32x4;
typedef __attribute__((ext_vector_type(8))) short bf16x8;

#define MFMA_BF16(a,b,c) __builtin_amdgcn_mfma_f32_16x16x32_bf16(a,b,c,0,0,0)

#define GL2LDS(gp, lp) __builtin_amdgcn_global_load_lds( \
    (const __attribute__((address_space(1))) void*)(gp), \
    (__attribute__((address_space(3))) void*)(lp), 16, 0, 0)

__device__ __forceinline__ short f2bf(float f) {
    union { float f; unsigned u; } v; v.f = f;
    unsigned r = v.u + 0x7FFFu + ((v.u >> 16) & 1u);
    return (short)(r >> 16);
}
__device__ __forceinline__ float bf2f(short s) {
    union { unsigned u; float f; } v; v.u = ((unsigned)(unsigned short)s) << 16;
    return v.f;
}

// ---------------------------------------------------------------------------
// One merged converter: flat grid 7257.
// [0,4096): x -> xh/xl split.  [4096,7168): six W -> W^T bf16.  [7168,7257): rel.
// ---------------------------------------------------------------------------
__global__ __launch_bounds__(256) void convert_all(
    const float* __restrict__ x,
    const float* __restrict__ Wq, const float* __restrict__ Wk,
    const float* __restrict__ Wv, const float* __restrict__ Wo,
    const float* __restrict__ W1, const float* __restrict__ W2,
    const float* __restrict__ relk, const float* __restrict__ relv,
    short* __restrict__ xh, short* __restrict__ xl,
    short* __restrict__ wqh, short* __restrict__ wql,
    short* __restrict__ wkh, short* __restrict__ wkl,
    short* __restrict__ wvT, short* __restrict__ woT,
    short* __restrict__ w1T, short* __restrict__ w2T,
    short* __restrict__ rh, short* __restrict__ rl, short* __restrict__ relvT)
{
    const int tid = threadIdx.x;
    int bid = blockIdx.x;
    if (bid < 4096) {
        int t = bid*256 + tid;
        float4 v = ((const float4*)x)[t];
        short h0 = f2bf(v.x), h1 = f2bf(v.y), h2 = f2bf(v.z), h3 = f2bf(v.w);
        short4 hv; hv.x=h0; hv.y=h1; hv.z=h2; hv.w=h3;
        short4 lv;
        lv.x = f2bf(v.x - bf2f(h0)); lv.y = f2bf(v.y - bf2f(h1));
        lv.z = f2bf(v.z - bf2f(h2)); lv.w = f2bf(v.w - bf2f(h3));
        ((short4*)xh)[t] = hv;
        ((short4*)xl)[t] = lv;
        return;
    }
    if (bid >= 7168) {
        int rb = bid - 7168;
        if (rb < 17) {
            int t = rb*256 + tid;
            if (t >= 272*64/4) return;
            float4 v = ((const float4*)relk)[t];
            short4 hv; hv.x=f2bf(v.x); hv.y=f2bf(v.y); hv.z=f2bf(v.z); hv.w=f2bf(v.w);
            short4 lv;
            lv.x = f2bf(v.x - bf2f(hv.x)); lv.y = f2bf(v.y - bf2f(hv.y));
            lv.z = f2bf(v.z - bf2f(hv.z)); lv.w = f2bf(v.w - bf2f(hv.w));
            ((short4*)rh)[t] = hv;
            ((short4*)rl)[t] = lv;
        } else {
            int t = (rb - 17)*256 + tid;
            if (t >= 64*288) return;
            int d = t / 288, o = t % 288;
            relvT[t] = (o <= 256) ? f2bf(relv[(size_t)o*DH_ + d]) : (short)0;
        }
        return;
    }
    int b = bid - 4096;
    const float* src; short* th; short* tl = nullptr; int K, N, bx, by;
    if (b < 256)        { src=Wq; th=wqh; tl=wql; K=1024; N=1024; bx=b&15; by=b>>4; }
    else if (b < 512)   { b-=256;  src=Wk; th=wkh; tl=wkl; K=1024; N=1024; bx=b&15; by=b>>4; }
    else if (b < 768)   { b-=512;  src=Wv; th=wvT; K=1024; N=1024; bx=b&15; by=b>>4; }
    else if (b < 1024)  { b-=768;  src=Wo; th=woT; K=1024; N=1024; bx=b&15; by=b>>4; }
    else if (b < 2048)  { b-=1024; src=W1; th=w1T; K=1024; N=4096; bx=b&63; by=b>>6; }
    else                { b-=2048; src=W2; th=w2T; K=4096; N=1024; bx=b&15; by=b>>4; }
    __shared__ float tile[64][65];
    const int k0 = by*64, n0 = bx*64;
    #pragma unroll
    for (int u = 0; u < 4; ++u) {
        int s = u*256 + tid;
        int rr = s>>4, cc = (s&15)*4;
        float4 v = *(const float4*)(src + (size_t)(k0+rr)*N + n0 + cc);
        tile[rr][cc] = v.x; tile[rr][cc+1] = v.y; tile[rr][cc+2] = v.z; tile[rr][cc+3] = v.w;
    }
    __syncthreads();
    #pragma unroll
    for (int u = 0; u < 4; ++u) {
        int s = u*256 + tid;
        int nn = s>>4, kk = (s&15)*4;
        size_t ob = (size_t)(n0+nn)*K + k0 + kk;
        float v0 = tile[kk+0][nn], v1 = tile[kk+1][nn], v2 = tile[kk+2][nn], v3 = tile[kk+3][nn];
        short4 hv; hv.x=f2bf(v0); hv.y=f2bf(v1); hv.z=f2bf(v2); hv.w=f2bf(v3);
        *(short4*)(th + ob) = hv;
        if (tl) {
            short4 lv;
            lv.x = f2bf(v0 - bf2f(hv.x)); lv.y = f2bf(v1 - bf2f(hv.y));
            lv.z = f2bf(v2 - bf2f(hv.z)); lv.w = f2bf(v3 - bf2f(hv.w));
            *(short4*)(tl + ob) = lv;
        }
    }
}

// ---------------------------------------------------------------------------
// MFMA GEMM: C = A(MxK) @ Bt(NxK)^T + bias.  BK=64, swizzled LDS.
// BN=128: 256 threads / 4 waves, wave = 64x64 (MF=4).
// BN=64 : 512 threads / 8 waves, wave = 16x64 (MF=1).
// ---------------------------------------------------------------------------
template<int EPI, bool SPLIT, int BN>
__global__ __launch_bounds__(BN == 64 ? 512 : 256) void gemm_mfma(
    const short* __restrict__ Ah, const short* __restrict__ Al,
    const short* __restrict__ Bh, const short* __restrict__ Bl,
    const float* __restrict__ bias, const float* __restrict__ res,
    void* __restrict__ out1, void* __restrict__ out2,
    int M, int N, int K)
{
    constexpr int NT = (BN == 64) ? 512 : 256;
    constexpr int MF = (BN == 128) ? 4 : 1;
    __shared__ short AsH[128*64], BsH[BN*64];
    __shared__ short AsL[SPLIT ? 128*64 : 8], BsL[SPLIT ? BN*64 : 8];
    const int tid = threadIdx.x, lane = tid & 63, w = tid >> 6;
    const int m0 = blockIdx.y*128, n0 = blockIdx.x*BN;
    const int wm = (BN == 128) ? (w>>1)*64 : w*16;
    const int wn = (BN == 128) ? (w&1)*64 : 0;
    f32x4 acc[MF][4] = {};
    for (int k0 = 0; k0 < K; k0 += 64) {
        __syncthreads();
        #pragma unroll
        for (int u = 0; u < 128*8/NT; ++u) {
            int s = u*NT + tid;
            int row = s >> 3, sc = ((s & 7)*16) ^ ((row & 7) << 4);
            GL2LDS((const char*)(Ah + (size_t)(m0+row)*K + k0) + sc, &AsH[(u*NT + w*64)*8]);
            if constexpr (SPLIT)
                GL2LDS((const char*)(Al + (size_t)(m0+row)*K + k0) + sc, &AsL[(u*NT + w*64)*8]);
        }
        #pragma unroll
        for (int u = 0; u < BN*8/NT; ++u) {
            int s = u*NT + tid;
            int row = s >> 3, sc = ((s & 7)*16) ^ ((row & 7) << 4);
            GL2LDS((const char*)(Bh + (size_t)(n0+row)*K + k0) + sc, &BsH[(u*NT + w*64)*8]);
            if constexpr (SPLIT)
                GL2LDS((const char*)(Bl + (size_t)(n0+row)*K + k0) + sc, &BsL[(u*NT + w*64)*8]);
        }
        asm volatile("s_waitcnt vmcnt(0)" ::: "memory");
        __syncthreads();
        #pragma unroll
        for (int ks = 0; ks < 2; ++ks) {
            const int kb = ks*64 + (lane >> 4)*16;
            bf16x8 aH[MF], bH[4], aL[MF], bL[4];
            #pragma unroll
            for (int f = 0; f < MF; ++f) {
                int row = wm + f*16 + (lane & 15);
                int off = row*128 + (kb ^ ((row & 7) << 4));
                aH[f] = *(const bf16x8*)((char*)AsH + off);
                if constexpr (SPLIT) aL[f] = *(const bf16x8*)((char*)AsL + off);
            }
            #pragma unroll
            for (int f = 0; f < 4; ++f) {
                int row = wn + f*16 + (lane & 15);
                int off = row*128 + (kb ^ ((row & 7) << 4));
                bH[f] = *(const bf16x8*)((char*)BsH + off);
                if constexpr (SPLIT) bL[f] = *(const bf16x8*)((char*)BsL + off);
            }
            #pragma unroll
            for (int mf = 0; mf < MF; ++mf)
            #pragma unroll
            for (int nf = 0; nf < 4; ++nf) {
                acc[mf][nf] = MFMA_BF16(aH[mf], bH[nf], acc[mf][nf]);
                if constexpr (SPLIT) {
                    acc[mf][nf] = MFMA_BF16(aH[mf], bL[nf], acc[mf][nf]);
                    acc[mf][nf] = MFMA_BF16(aL[mf], bH[nf], acc[mf][nf]);
                }
            }
        }
    }
    #pragma unroll
    for (int mf = 0; mf < MF; ++mf)
    #pragma unroll
    for (int nf = 0; nf < 4; ++nf)
    #pragma unroll
    for (int r = 0; r < 4; ++r) {
        int m = m0 + wm + mf*16 + ((lane>>4)<<2) + r;
        int n = n0 + wn + nf*16 + (lane&15);
        float v = acc[mf][nf][r] + bias[n];
        if (EPI == 0) {
            ((float*)out1)[(size_t)m*N + n] = v;
        } else if (EPI == 3) {
            ((short*)out1)[(size_t)m*N + n] = f2bf(fmaxf(v, 0.f));
        } else if (EPI == 4) {
            ((float*)out1)[(size_t)m*N + n] = v + res[(size_t)m*N + n];
        }
    }
}

// ---------------------------------------------------------------------------
// Merged QKV GEMM: one dispatch, grid (48, 32), 512 threads / 8 waves.
// region = blockIdx.x>>4: 0 -> Q (split), 1 -> K (split), 2 -> V (v^T out).
// ---------------------------------------------------------------------------
__global__ __launch_bounds__(512) void qkv_mfma(
    const short* __restrict__ xh, const short* __restrict__ xl,
    const short* __restrict__ wqh, const short* __restrict__ wql,
    const short* __restrict__ wkh, const short* __restrict__ wkl,
    const short* __restrict__ wvT,
    const float* __restrict__ bq, const float* __restrict__ bk,
    const float* __restrict__ bv,
    short* __restrict__ qhB, short* __restrict__ qlB,
    short* __restrict__ khB, short* __restrict__ klB,
    short* __restrict__ vTout)
{
    const int region = blockIdx.x >> 4;
    const int n0 = (blockIdx.x & 15)*64;
    const int m0 = blockIdx.y*128;
    const bool split = region < 2;
    const short* Bh = region==0 ? wqh : (region==1 ? wkh : wvT);
    const short* Bl = region==0 ? wql : wkl;
    const float* bias = region==0 ? bq : (region==1 ? bk : bv);
    const int K = HID_;
    __shared__ short AsH[128*64], AsL[128*64], BsH[64*64], BsL[64*64];
    const int tid = threadIdx.x, lane = tid & 63, w = tid >> 6;
    const int wm = w*16;
    f32x4 acc[4] = {};
    for (int k0 = 0; k0 < K; k0 += 64) {
        __syncthreads();
        #pragma unroll
        for (int u = 0; u < 2; ++u) {
            int s = u*512 + tid;
            int row = s >> 3, sc = ((s & 7)*16) ^ ((row & 7) << 4);
            GL2LDS((const char*)(xh + (size_t)(m0+row)*K + k0) + sc, &AsH[(u*512 + w*64)*8]);
            if (split)
                GL2LDS((const char*)(xl + (size_t)(m0+row)*K + k0) + sc, &AsL[(u*512 + w*64)*8]);
        }
        {
            int s = tid;
            int row = s >> 3, sc = ((s & 7)*16) ^ ((row & 7) << 4);
            GL2LDS((const char*)(Bh + (size_t)(n0+row)*K + k0) + sc, &BsH[(w*64)*8]);
            if (split)
                GL2LDS((const char*)(Bl + (size_t)(n0+row)*K + k0) + sc, &BsL[(w*64)*8]);
        }
        asm volatile("s_waitcnt vmcnt(0)" ::: "memory");
        __syncthreads();
        #pragma unroll
        for (int ks = 0; ks < 2; ++ks) {
            const int kb = ks*64 + (lane >> 4)*16;
            bf16x8 aH, aL, bH[4], bL[4];
            {
                int row = wm + (lane & 15);
                int off = row*128 + (kb ^ ((row & 7) << 4));
                aH = *(const bf16x8*)((char*)AsH + off);
                if (split) aL = *(const bf16x8*)((char*)AsL + off);
            }
            #pragma unroll
            for (int f = 0; f < 4; ++f) {
                int row = f*16 + (lane & 15);
                int off = row*128 + (kb ^ ((row & 7) << 4));
                bH[f] = *(const bf16x8*)((char*)BsH + off);
                if (split) bL[f] = *(const bf16x8*)((char*)BsL + off);
            }
            #pragma unroll
            for (int nf = 0; nf < 4; ++nf) {
                acc[nf] = MFMA_BF16(aH, bH[nf], acc[nf]);
                if (split) {
                    acc[nf] = MFMA_BF16(aH, bL[nf], acc[nf]);
                    acc[nf] = MFMA_BF16(aL, bH[nf], acc[nf]);
                }
            }
        }
    }
    short* outH = region==0 ? qhB : khB;
    short* outL = region==0 ? qlB : klB;
    #pragma unroll
    for (int nf = 0; nf < 4; ++nf)
    #pragma unroll
    for (int r = 0; r < 4; ++r) {
        int m = m0 + wm + ((lane>>4)<<2) + r;
        int n = n0 + nf*16 + (lane&15);
        float v = acc[nf][r] + bias[n];
        int bb = m >> 10, ii = m & (S_-1), hh = n >> 6, dd = n & (DH_-1);
        if (region < 2) {
            size_t idx = (((size_t)bb*H_ + hh)*S_ + ii)*DH_ + dd;
            short hv = f2bf(v);
            outH[idx] = hv;
            outL[idx] = f2bf(v - bf2f(hv));
        } else {
            size_t idx = (((size_t)bb*H_ + hh)*DH_ + dd)*S_ + ii;
            vTout[idx] = f2bf(v);
        }
    }
}

// ---------------------------------------------------------------------------
// logits = QK^T + gather(R),  R = q @ relk[0..256]^T  (split-bf16 MFMA)
// Rl stored bf16 (LDS 59 -> 41 KB => 3 blocks/CU).  Stats + logits use the
// same stored R value, so the rounding largely cancels through the softmax.
// ---------------------------------------------------------------------------
__global__ __launch_bounds__(256) void qk_rel_kernel(
    const short* __restrict__ qh, const short* __restrict__ ql,
    const short* __restrict__ kh, const short* __restrict__ kl,
    const short* __restrict__ rkh, const short* __restrict__ rkl,
    float* __restrict__ Wt, float* __restrict__ pmP, float* __restrict__ psP)
{
    const int bid = blockIdx.x;
    const int bh = bid & 63, ib = bid >> 6;
    const int i0 = ib*32;
    const int tid = threadIdx.x, lane = tid & 63, w = tid >> 6;
    __shared__ short Qh[32*64], Ql[32*64];
    __shared__ short Kh[64*64], Kl[64*64];
    __shared__ short Rl[32*273];
    {
        int row = tid >> 3;
        int sc = ((tid & 7)*16) ^ ((row & 7) << 4);
        const char* qb = (const char*)(qh + ((size_t)bh*S_ + i0 + row)*DH_);
        const char* lb = (const char*)(ql + ((size_t)bh*S_ + i0 + row)*DH_);
        GL2LDS(qb + sc, &Qh[(w*64)*8]);
        GL2LDS(lb + sc, &Ql[(w*64)*8]);
    }
    asm volatile("s_waitcnt vmcnt(0)" ::: "memory");
    __syncthreads();
    for (int nf = w; nf < 17; nf += 4) {
        f32x4 racc[2] = {};
        #pragma unroll
        for (int ks = 0; ks < 2; ++ks) {
            const size_t ro = (size_t)(nf*16 + (lane&15))*DH_ + ks*32 + (lane>>4)*8;
            bf16x8 bHf = *(const bf16x8*)(rkh + ro);
            bf16x8 bLf = *(const bf16x8*)(rkl + ro);
            const int kb = ks*64 + (lane >> 4)*16;
            #pragma unroll
            for (int mf = 0; mf < 2; ++mf) {
                int row = mf*16 + (lane & 15);
                int off = row*128 + (kb ^ ((row & 7) << 4));
                bf16x8 A  = *(const bf16x8*)((char*)Qh + off);
                bf16x8 AL = *(const bf16x8*)((char*)Ql + off);
                racc[mf] = MFMA_BF16(A,  bHf, racc[mf]);
                racc[mf] = MFMA_BF16(A,  bLf, racc[mf]);
                racc[mf] = MFMA_BF16(AL, bHf, racc[mf]);
            }
        }
        #pragma unroll
        for (int mf = 0; mf < 2; ++mf)
        #pragma unroll
        for (int r = 0; r < 4; ++r)
            Rl[(mf*16 + ((lane>>4)<<2) + r)*273 + nf*16 + (lane&15)] = f2bf(racc[mf][r]);
    }
    const int ilim = i0 + 31;
    for (int j0 = 0; j0 <= ilim; j0 += 64) {
        __syncthreads();
        {
            int s0 = tid, s1 = 256 + tid;
            int r0 = s0 >> 3, r1 = s1 >> 3;
            int c0 = ((s0 & 7)*16) ^ ((r0 & 7) << 4);
            int c1 = ((s1 & 7)*16) ^ ((r1 & 7) << 4);
            const char* k0b = (const char*)(kh + ((size_t)bh*S_ + j0 + r0)*DH_);
            const char* k1b = (const char*)(kh + ((size_t)bh*S_ + j0 + r1)*DH_);
            const char* l0b = (const char*)(kl + ((size_t)bh*S_ + j0 + r0)*DH_);
            const char* l1b = (const char*)(kl + ((size_t)bh*S_ + j0 + r1)*DH_);
            GL2LDS(k0b + c0, &Kh[(w*64)*8]);
            GL2LDS(k1b + c1, &Kh[(256 + w*64)*8]);
            GL2LDS(l0b + c0, &Kl[(w*64)*8]);
            GL2LDS(l1b + c1, &Kl[(256 + w*64)*8]);
        }
        asm volatile("s_waitcnt vmcnt(0)" ::: "memory");
        __syncthreads();
        const int jb = j0 + w*16;
        if (jb <= ilim) {
            f32x4 acc[2] = {};
            #pragma unroll
            for (int ks = 0; ks < 2; ++ks) {
                const int kb = ks*64 + (lane >> 4)*16;
                int rowB = w*16 + (lane & 15);
                int offB = rowB*128 + (kb ^ ((rowB & 7) << 4));
                bf16x8 bHf = *(const bf16x8*)((char*)Kh + offB);
                bf16x8 bLf = *(const bf16x8*)((char*)Kl + offB);
                #pragma unroll
                for (int mf = 0; mf < 2; ++mf) {
                    int row = mf*16 + (lane & 15);
                    int off = row*128 + (kb ^ ((row & 7) << 4));
                    bf16x8 A  = *(const bf16x8*)((char*)Qh + off);
                    bf16x8 AL = *(const bf16x8*)((char*)Ql + off);
                    acc[mf] = MFMA_BF16(A,  bHf, acc[mf]);
                    acc[mf] = MFMA_BF16(A,  bLf, acc[mf]);
                    acc[mf] = MFMA_BF16(AL, bHf, acc[mf]);
                }
            }
            const int j = jb + (lane&15);
            float lreg[2][4];
            #pragma unroll
            for (int mf = 0; mf < 2; ++mf)
            #pragma unroll
            for (int r = 0; r < 4; ++r) {
                int i = i0 + mf*16 + ((lane>>4)<<2) + r;
                int o = j - i + 256;
                o = o < 0 ? 0 : (o > 272 ? 272 : o);
                float l = acc[mf][r] + bf2f(Rl[(i - i0)*273 + o]);
                Wt[((size_t)bh*S_ + i)*S_ + j] = l;
                lreg[mf][r] = (i >= j) ? l : -INFINITY;
            }
            float pm = -INFINITY;
            #pragma unroll
            for (int mf = 0; mf < 2; ++mf)
            #pragma unroll
            for (int r = 0; r < 4; ++r) pm = fmaxf(pm, lreg[mf][r]);
            float ps = 0.f;
            #pragma unroll
            for (int mf = 0; mf < 2; ++mf)
            #pragma unroll
            for (int r = 0; r < 4; ++r)
                if (lreg[mf][r] > -INFINITY) ps += __expf(lreg[mf][r] - pm);
            #pragma unroll
            for (int d = 16; d <= 32; d <<= 1) {
                float om = __shfl_xor(pm, d, 64);
                float os = __shfl_xor(ps, d, 64);
                float nm = fmaxf(pm, om);
                float pa = (pm > -INFINITY) ? ps*__expf(pm - nm) : 0.f;
                float pb = (om > -INFINITY) ? os*__expf(om - nm) : 0.f;
                pm = nm; ps = pa + pb;
            }
            if ((lane >> 4) == 0) {
                size_t sidx = ((size_t)bh*32 + ib)*S_ + j;
                pmP[sidx] = pm;
                psP[sidx] = ps;
            }
        }
    }
}

// ---------------------------------------------------------------------------
// Combine the 32 per-i-tile partials into per-column M and 1/D.
// ---------------------------------------------------------------------------
__global__ __launch_bounds__(256) void colstats_kernel(
    const float* __restrict__ pmP, const float* __restrict__ psP,
    float* __restrict__ Mcol, float* __restrict__ Dinv)
{
    const int bh = blockIdx.y;
    const int j = blockIdx.x*256 + threadIdx.x;
    const int it0 = j >> 5;
    float M = -INFINITY;
    for (int it = it0; it < 32; ++it)
        M = fmaxf(M, pmP[((size_t)bh*32 + it)*S_ + j]);
    float D = 0.f;
    for (int it = it0; it < 32; ++it) {
        float pm = pmP[((size_t)bh*32 + it)*S_ + j];
        if (pm > -INFINITY)
            D += psP[((size_t)bh*32 + it)*S_ + j] * __expf(pm - M);
    }
    Mcol[(size_t)bh*S_ + j] = M;
    Dinv[(size_t)bh*S_ + j] = 1.f / D;
}

// ---------------------------------------------------------------------------
// Fused normalize + PV + rel-vals band GEMM + upper-triangle zero fill.
// 64-row i-blocks, 512 threads / 8 waves, grid 1024 (bh = bid&63, iblk=bid>>6).
// LDS 52 KB -> 3 blocks/CU = 24 waves/CU; barriers and V staging per unit of
// work halve vs the 32-row version.
// ---------------------------------------------------------------------------
__global__ __launch_bounds__(512) void pv_norm_kernel(
    float* __restrict__ Wt, const short* __restrict__ vt,
    const float* __restrict__ Mcol, const float* __restrict__ Dinv,
    const short* __restrict__ relvT, short* __restrict__ attnctx)
{
    const int bid = blockIdx.x;
    const int bh = bid & 63, iblk = bid >> 6;
    const int i0 = iblk*64;
    const int b = bh >> 4, h = bh & (H_-1);
    const int tid = threadIdx.x, lane = tid & 63, w = tid >> 6;   // w 0..7
    __shared__ __align__(16) char smem[53248];
    short* Vs   = (short*)smem;              // [64][64] bf16, swizzled (8 KB)
    short* Ws   = (short*)(smem + 8192);     // [64][64] bf16, swizzled (8 KB)
    short* band = (short*)(smem + 16384);    // [64][288] bf16 (36 KB)
    float* Wb = Wt + (size_t)bh*S_*S_;
    const int cg = (tid & 15)*4;             // 4-column group per thread
    const int rq = tid >> 4;                 // 0..31; rows rq and rq+32
    // zero the band: 36864 B = 2304 int4
    #pragma unroll
    for (int u = 0; u < 5; ++u) {
        int s = u*512 + tid;
        if (s < 2304) ((int4*)band)[s] = make_int4(0,0,0,0);
    }
    float rowsum[2] = {}, bandsum[2] = {};
    f32x4 acc[2] = {};
    const int if_ = w & 3, df0 = (w >> 2)*2; // 8 waves = 4 i-frags x 2 d-pairs
    const int vr = tid >> 3, vc = (tid & 7)*8;
    const size_t vbase = (size_t)bh*DH_*S_;
    // prologue: prefetch logits tile j0=0 and column stats
    float4 Lreg[2];
    #pragma unroll
    for (int u = 0; u < 2; ++u)
        Lreg[u] = *(const float4*)(Wb + (size_t)(i0 + u*32 + rq)*S_ + cg);
    float4 Mj = *(const float4*)(Mcol + (size_t)bh*S_ + cg);
    float4 Dj = *(const float4*)(Dinv + (size_t)bh*S_ + cg);
    __syncthreads();
    for (int j0 = 0; j0 <= i0; j0 += 64) {
        // V tile (64x64) to registers: one bf16x8 per thread
        bf16x8 v0 = *(const bf16x8*)(vt + vbase + (size_t)vr*S_ + j0 + vc);
        float wv[2][4];
        #pragma unroll
        for (int u = 0; u < 2; ++u) {
            int ig = i0 + u*32 + rq;
            wv[u][0] = (ig >= j0+cg+0) ? __expf(Lreg[u].x - Mj.x)*Dj.x : 0.f;
            wv[u][1] = (ig >= j0+cg+1) ? __expf(Lreg[u].y - Mj.y)*Dj.y : 0.f;
            wv[u][2] = (ig >= j0+cg+2) ? __expf(Lreg[u].z - Mj.z)*Dj.z : 0.f;
            wv[u][3] = (ig >= j0+cg+3) ? __expf(Lreg[u].w - Mj.w)*Dj.w : 0.f;
        }
        #pragma unroll
        for (int u = 0; u < 2; ++u) {
            float4 w4; w4.x=wv[u][0]; w4.y=wv[u][1]; w4.z=wv[u][2]; w4.w=wv[u][3];
            *(float4*)(Wb + (size_t)(i0 + u*32 + rq)*S_ + j0 + cg) = w4;
        }
        float4 Lnext[2] = {};
        float4 Mn = Mj, Dn = Dj;
        const int j1 = j0 + 64;
        if (j1 <= i0) {
            #pragma unroll
            for (int u = 0; u < 2; ++u)
                Lnext[u] = *(const float4*)(Wb + (size_t)(i0 + u*32 + rq)*S_ + j1 + cg);
            Mn = *(const float4*)(Mcol + (size_t)bh*S_ + j1 + cg);
            Dn = *(const float4*)(Dinv + (size_t)bh*S_ + j1 + cg);
        }
        // LDS writes: V (swizzled), W (swizzled bf16), band scatter + rowsum
        *(bf16x8*)((char*)Vs + vr*128 + ((vc*2) ^ ((vr & 7) << 4))) = v0;
        #pragma unroll
        for (int u = 0; u < 2; ++u) {
            int r = u*32 + rq;
            int ig = i0 + r;
            short4 wb4; wb4.x=f2bf(wv[u][0]); wb4.y=f2bf(wv[u][1]);
            wb4.z=f2bf(wv[u][2]); wb4.w=f2bf(wv[u][3]);
            *(short4*)((char*)Ws + r*128 + ((cg*2) ^ ((r & 7) << 4))) = wb4;
            rowsum[u] += wv[u][0] + wv[u][1] + wv[u][2] + wv[u][3];
            const int obase = j0 + cg - ig + 256;
            #pragma unroll
            for (int c = 0; c < 4; ++c) {
                int o = obase + c;
                if (o >= 1 && o <= 256) {
                    band[r*288 + o] = f2bf(wv[u][c]);
                    bandsum[u] += wv[u][c];
                }
            }
        }
        __syncthreads();
        // PV MFMA: out^T(d, i) += V^T(d, j) @ W^T(j, i)
        const int kq16 = (lane >> 4)*16;
        #pragma unroll
        for (int ks = 0; ks < 2; ++ks) {
            bf16x8 bw;
            {
                int row = if_*16 + (lane & 15);
                bw = *(const bf16x8*)((char*)Ws + row*128 +
                      ((ks*64 + kq16) ^ ((row & 7) << 4)));
            }
            #pragma unroll
            for (int dfi = 0; dfi < 2; ++dfi) {
                int row = (df0 + dfi)*16 + (lane & 15);
                bf16x8 av = *(const bf16x8*)((char*)Vs + row*128 +
                      ((ks*64 + kq16) ^ ((row & 7) << 4)));
                acc[dfi] = MFMA_BF16(av, bw, acc[dfi]);
            }
        }
        __syncthreads();
        #pragma unroll
        for (int u = 0; u < 2; ++u) Lreg[u] = Lnext[u];
        Mj = Mn; Dj = Dn;
    }
    // tail = rowsum - bandsum, reduced over the 16 lanes sharing each row
    #pragma unroll
    for (int u = 0; u < 2; ++u) {
        #pragma unroll
        for (int m = 1; m <= 8; m <<= 1) {
            rowsum[u]  += __shfl_xor(rowsum[u],  m, 64);
            bandsum[u] += __shfl_xor(bandsum[u], m, 64);
        }
    }
    if ((tid & 15) == 0) {
        #pragma unroll
        for (int u = 0; u < 2; ++u)
            band[(u*32 + rq)*288] = f2bf(rowsum[u] - bandsum[u]);
    }
    __syncthreads();
    // rel-vals MFMA: out(i, d) = band(i, :288) @ relvT(d, :288)^T
    f32x4 acc2[2] = {};
    const int mf_ = w & 3, nf0 = (w >> 2)*2;
    const int kq = (lane >> 4)*8;
    #pragma unroll
    for (int ks = 0; ks < 9; ++ks) {
        bf16x8 a = *(const bf16x8*)&band[(mf_*16 + (lane & 15))*288 + ks*32 + kq];
        #pragma unroll
        for (int nfi = 0; nfi < 2; ++nfi) {
            bf16x8 bb = *(const bf16x8*)&relvT[(size_t)((nf0+nfi)*16 + (lane & 15))*288 + ks*32 + kq];
            acc2[nfi] = MFMA_BF16(a, bb, acc2[nfi]);
        }
    }
    __syncthreads();
    float* Os = (float*)band;                // [64][68] fp32 (17408 B, fits)
    #pragma unroll
    for (int dfi = 0; dfi < 2; ++dfi)
    #pragma unroll
    for (int r = 0; r < 4; ++r) {
        int d  = (df0 + dfi)*16 + ((lane >> 4) << 2) + r;
        int il = if_*16 + (lane & 15);
        Os[il*68 + d] = acc[dfi][r];
    }
    __syncthreads();
    #pragma unroll
    for (int nfi = 0; nfi < 2; ++nfi)
    #pragma unroll
    for (int rr = 0; rr < 4; ++rr) {
        int ii = mf_*16 + ((lane >> 4) << 2) + rr;
        int d  = (nf0 + nfi)*16 + (lane & 15);
        Os[ii*68 + d] += acc2[nfi][rr];
    }
    __syncthreads();
    {
        int row = tid >> 3, q8 = (tid & 7)*8;
        short* dst = attnctx + ((size_t)b*S_ + i0 + row)*HID_ + h*DH_ + q8;
        short tmp[8];
        #pragma unroll
        for (int e = 0; e < 8; ++e) tmp[e] = f2bf(Os[row*68 + q8 + e]);
        *(int4*)(dst) = *(int4*)(tmp);
    }
    // fused zero fill of the upper region (j >= i0+64) for these 64 rows
    {
        const int c0 = i0 + 64;
        if (c0 < S_) {
            float4 z; z.x = 0.f; z.y = 0.f; z.z = 0.f; z.w = 0.f;
            const int r = tid >> 3;
            float* rowp = Wb + (size_t)(i0 + r)*S_;
            for (int c = c0 + (tid & 7)*4; c < S_; c += 32)
                *(float4*)(rowp + c) = z;
        }
    }
}

// ---------------------------------------------------------------------------
// ctx = LayerNorm(y + x)*g + b + x ; also bf16 copy for FFN
// ---------------------------------------------------------------------------
__global__ __launch_bounds__(256) void ln_kernel(
    const float* __restrict__ y, const float* __restrict__ x,
    const float* __restrict__ g, const float* __restrict__ bta,
    float* __restrict__ ctx, short* __restrict__ ctxb)
{
    const int row = blockIdx.x;
    const int tid = threadIdx.x;
    float t[4], xv[4];
    #pragma unroll
    for (int u = 0; u < 4; ++u) {
        int c = tid + u*256;
        xv[u] = x[(size_t)row*HID_ + c];
        t[u]  = y[(size_t)row*HID_ + c] + xv[u];
    }
    __shared__ float red[4];
    float s = t[0] + t[1] + t[2] + t[3];
    #pragma unroll
    for (int o = 32; o > 0; o >>= 1) s += __shfl_down(s, o, 64);
    if ((tid & 63) == 0) red[tid >> 6] = s;
    __syncthreads();
    const float mean = (red[0]+red[1]+red[2]+red[3]) * (1.f/1024.f);
    float vsum = 0.f;
    #pragma unroll
    for (int u = 0; u < 4; ++u) { float dd = t[u]-mean; vsum += dd*dd; }
    __syncthreads();
    #pragma unroll
    for (int o = 32; o > 0; o >>= 1) vsum += __shfl_down(vsum, o, 64);
    if ((tid & 63) == 0) red[tid >> 6] = vsum;
    __syncthreads();
    const float var = (red[0]+red[1]+red[2]+red[3]) * (1.f/1024.f);
    const float rstd = rsqrtf(var + 1e-5f);
    #pragma unroll
    for (int u = 0; u < 4; ++u) {
        int c = tid + u*256;
        float cv = (t[u]-mean)*rstd*g[c] + bta[c] + xv[u];
        ctx[(size_t)row*HID_ + c] = cv;
        ctxb[(size_t)row*HID_ + c] = f2bf(cv);
    }
}

// ---------------------------------------------------------------------------
extern "C" void kernel_launch(void* const* d_in, const int* in_sizes, int n_in,
                              void* d_out, int out_size, void* d_ws, size_t ws_size,
                              hipStream_t stream)
{
    const float* x    = (const float*)d_in[0];
    const float* Wq   = (const float*)d_in[1];
    const float* bq   = (const float*)d_in[2];
    const float* Wk   = (const float*)d_in[3];
    const float* bk   = (const float*)d_in[4];
    const float* Wv   = (const float*)d_in[5];
    const float* bv   = (const float*)d_in[6];
    const float* relk = (const float*)d_in[7];
    const float* relv = (const float*)d_in[8];
    const float* Wo   = (const float*)d_in[9];
    const float* bo   = (const float*)d_in[10];
    const float* lng  = (const float*)d_in[11];
    const float* lnb  = (const float*)d_in[12];
    const float* W1   = (const float*)d_in[13];
    const float* b1   = (const float*)d_in[14];
    const float* W2   = (const float*)d_in[15];
    const float* b2   = (const float*)d_in[16];

    float* contexts = (float*)d_out;                       // (B,S,HID) fp32
    float* Wt = contexts + (size_t)B_*S_*HID_;             // weights (B,H,S,S) fp32

    char* ws = (char*)d_ws;
    short* xh   = (short*)(ws + 0);            // 8 MB  (region reused as y fp32)
    short* xl   = (short*)(ws + 8388608);
    float* y    = (float*)(ws + 0);            // 16 MB (after QKV done)
    short* wqh  = (short*)(ws + 16777216);
    short* wql  = (short*)(ws + 18874368);
    short* wkh  = (short*)(ws + 20971520);
    short* wkl  = (short*)(ws + 23068672);
    short* wvT  = (short*)(ws + 25165824);
    short* woT  = (short*)(ws + 27262976);
    short* w1T  = (short*)(ws + 29360128);
    short* w2T  = (short*)(ws + 37748736);
    short* rkh  = (short*)(ws + 46137344);
    short* rkl  = (short*)(ws + 46202880);
    short* qhB  = (short*)(ws + 46268416);     // q/k hi/lo (reused as h1)
    short* qlB  = (short*)(ws + 54657024);
    short* khB  = (short*)(ws + 63045632);
    short* klB  = (short*)(ws + 71434240);
    short* h1   = (short*)(ws + 46268416);     // 32 MB, overlaps dead q/k
    short* vT   = (short*)(ws + 79822848);     // 8 MB
    short* attn = (short*)(ws + 88211456);     // 8 MB
    float* ctx  = (float*)(ws + 96600064);     // 16 MB
    short* ctxb = (short*)(ws + 113377280);    // 8 MB
    float* pmP  = (float*)(ws + 121765888);    // 8 MB partial max
    float* psP  = (float*)(ws + 130154496);    // 8 MB partial sumexp
    float* Mcol = (float*)(ws + 138543104);    // 256 KB
    float* Dinv = (float*)(ws + 138805248);    // 256 KB
    short* relvT= (short*)(ws + 139067392);    // 36 KB [64][288] bf16

    const int M = B_*S_;
    dim3 blk(256), blk512(512);

    convert_all<<<7257, blk, 0, stream>>>(x, Wq, Wk, Wv, Wo, W1, W2, relk, relv,
                                          xh, xl, wqh, wql, wkh, wkl, wvT, woT,
                                          w1T, w2T, rkh, rkl, relvT);

    qkv_mfma<<<dim3(48,32), blk512, 0, stream>>>(xh, xl, wqh, wql, wkh, wkl, wvT,
                                                 bq, bk, bv, qhB, qlB, khB, klB, vT);

    qk_rel_kernel<<<2048, blk, 0, stream>>>(qhB, qlB, khB, klB, rkh, rkl, Wt, pmP, psP);
    colstats_kernel<<<dim3(4,64), blk, 0, stream>>>(pmP, psP, Mcol, Dinv);
    pv_norm_kernel<<<1024, blk512, 0, stream>>>(Wt, vT, Mcol, Dinv, relvT, attn);

    gemm_mfma<0,false,64><<<dim3(16,32), blk512, 0, stream>>>(attn, nullptr, woT, nullptr, bo, nullptr, y, nullptr, M, HID_, HID_);
    ln_kernel<<<M, blk, 0, stream>>>(y, x, lng, lnb, ctx, ctxb);
    gemm_mfma<3,false,128><<<dim3(32,32), blk, 0, stream>>>(ctxb, nullptr, w1T, nullptr, b1, nullptr, h1, nullptr, M, FF_, HID_);
    gemm_mfma<4,false,64><<<dim3(16,32), blk512, 0, stream>>>(h1, nullptr, w2T, nullptr, b2, ctx, contexts, nullptr, M, HID_, FF_);
}

// Round 16
// 455.461 us; speedup vs baseline: 1.0305x; 1.0305x over previous
//
#include <hip/hip_runtime.h>
#include <hip/hip_bf16.h>
#include <math.h>

#define B_   4
#define S_   1024
#define HID_ 1024
#define H_   16
#define DH_  64
#define FF_  4096
#define MREL_ 256

typedef __attribute__((ext_vector_type(4))) float f32x4;
typedef __attribute__((ext_vector_type(8))) short bf16x8;

#define MFMA_BF16(a,b,c) __builtin_amdgcn_mfma_f32_16x16x32_bf16(a,b,c,0,0,0)

#define GL2LDS(gp, lp) __builtin_amdgcn_global_load_lds( \
    (const __attribute__((address_space(1))) void*)(gp), \
    (__attribute__((address_space(3))) void*)(lp), 16, 0, 0)

__device__ __forceinline__ short f2bf(float f) {
    union { float f; unsigned u; } v; v.f = f;
    unsigned r = v.u + 0x7FFFu + ((v.u >> 16) & 1u);
    return (short)(r >> 16);
}
__device__ __forceinline__ float bf2f(short s) {
    union { unsigned u; float f; } v; v.u = ((unsigned)(unsigned short)s) << 16;
    return v.f;
}

// ---------------------------------------------------------------------------
// One merged converter: flat grid 7257.
// [0,4096): x -> xh/xl split.  [4096,7168): six W -> W^T bf16.  [7168,7257): rel.
// ---------------------------------------------------------------------------
__global__ __launch_bounds__(256) void convert_all(
    const float* __restrict__ x,
    const float* __restrict__ Wq, const float* __restrict__ Wk,
    const float* __restrict__ Wv, const float* __restrict__ Wo,
    const float* __restrict__ W1, const float* __restrict__ W2,
    const float* __restrict__ relk, const float* __restrict__ relv,
    short* __restrict__ xh, short* __restrict__ xl,
    short* __restrict__ wqh, short* __restrict__ wql,
    short* __restrict__ wkh, short* __restrict__ wkl,
    short* __restrict__ wvT, short* __restrict__ woT,
    short* __restrict__ w1T, short* __restrict__ w2T,
    short* __restrict__ rh, short* __restrict__ rl, short* __restrict__ relvT)
{
    const int tid = threadIdx.x;
    int bid = blockIdx.x;
    if (bid < 4096) {
        int t = bid*256 + tid;
        float4 v = ((const float4*)x)[t];
        short h0 = f2bf(v.x), h1 = f2bf(v.y), h2 = f2bf(v.z), h3 = f2bf(v.w);
        short4 hv; hv.x=h0; hv.y=h1; hv.z=h2; hv.w=h3;
        short4 lv;
        lv.x = f2bf(v.x - bf2f(h0)); lv.y = f2bf(v.y - bf2f(h1));
        lv.z = f2bf(v.z - bf2f(h2)); lv.w = f2bf(v.w - bf2f(h3));
        ((short4*)xh)[t] = hv;
        ((short4*)xl)[t] = lv;
        return;
    }
    if (bid >= 7168) {
        int rb = bid - 7168;
        if (rb < 17) {
            int t = rb*256 + tid;
            if (t >= 272*64/4) return;
            float4 v = ((const float4*)relk)[t];
            short4 hv; hv.x=f2bf(v.x); hv.y=f2bf(v.y); hv.z=f2bf(v.z); hv.w=f2bf(v.w);
            short4 lv;
            lv.x = f2bf(v.x - bf2f(hv.x)); lv.y = f2bf(v.y - bf2f(hv.y));
            lv.z = f2bf(v.z - bf2f(hv.z)); lv.w = f2bf(v.w - bf2f(hv.w));
            ((short4*)rh)[t] = hv;
            ((short4*)rl)[t] = lv;
        } else {
            int t = (rb - 17)*256 + tid;
            if (t >= 64*288) return;
            int d = t / 288, o = t % 288;
            relvT[t] = (o <= 256) ? f2bf(relv[(size_t)o*DH_ + d]) : (short)0;
        }
        return;
    }
    int b = bid - 4096;
    const float* src; short* th; short* tl = nullptr; int K, N, bx, by;
    if (b < 256)        { src=Wq; th=wqh; tl=wql; K=1024; N=1024; bx=b&15; by=b>>4; }
    else if (b < 512)   { b-=256;  src=Wk; th=wkh; tl=wkl; K=1024; N=1024; bx=b&15; by=b>>4; }
    else if (b < 768)   { b-=512;  src=Wv; th=wvT; K=1024; N=1024; bx=b&15; by=b>>4; }
    else if (b < 1024)  { b-=768;  src=Wo; th=woT; K=1024; N=1024; bx=b&15; by=b>>4; }
    else if (b < 2048)  { b-=1024; src=W1; th=w1T; K=1024; N=4096; bx=b&63; by=b>>6; }
    else                { b-=2048; src=W2; th=w2T; K=4096; N=1024; bx=b&15; by=b>>4; }
    __shared__ float tile[64][65];
    const int k0 = by*64, n0 = bx*64;
    #pragma unroll
    for (int u = 0; u < 4; ++u) {
        int s = u*256 + tid;
        int rr = s>>4, cc = (s&15)*4;
        float4 v = *(const float4*)(src + (size_t)(k0+rr)*N + n0 + cc);
        tile[rr][cc] = v.x; tile[rr][cc+1] = v.y; tile[rr][cc+2] = v.z; tile[rr][cc+3] = v.w;
    }
    __syncthreads();
    #pragma unroll
    for (int u = 0; u < 4; ++u) {
        int s = u*256 + tid;
        int nn = s>>4, kk = (s&15)*4;
        size_t ob = (size_t)(n0+nn)*K + k0 + kk;
        float v0 = tile[kk+0][nn], v1 = tile[kk+1][nn], v2 = tile[kk+2][nn], v3 = tile[kk+3][nn];
        short4 hv; hv.x=f2bf(v0); hv.y=f2bf(v1); hv.z=f2bf(v2); hv.w=f2bf(v3);
        *(short4*)(th + ob) = hv;
        if (tl) {
            short4 lv;
            lv.x = f2bf(v0 - bf2f(hv.x)); lv.y = f2bf(v1 - bf2f(hv.y));
            lv.z = f2bf(v2 - bf2f(hv.z)); lv.w = f2bf(v3 - bf2f(hv.w));
            *(short4*)(tl + ob) = lv;
        }
    }
}

// ---------------------------------------------------------------------------
// MFMA GEMM: C = A(MxK) @ Bt(NxK)^T + bias.  BK=64, swizzled LDS.
// BN=128: 256 threads / 4 waves, wave = 64x64 (MF=4).
// BN=64 : 512 threads / 8 waves, wave = 16x64 (MF=1).
// ---------------------------------------------------------------------------
template<int EPI, bool SPLIT, int BN>
__global__ __launch_bounds__(BN == 64 ? 512 : 256) void gemm_mfma(
    const short* __restrict__ Ah, const short* __restrict__ Al,
    const short* __restrict__ Bh, const short* __restrict__ Bl,
    const float* __restrict__ bias, const float* __restrict__ res,
    void* __restrict__ out1, void* __restrict__ out2,
    int M, int N, int K)
{
    constexpr int NT = (BN == 64) ? 512 : 256;
    constexpr int MF = (BN == 128) ? 4 : 1;
    __shared__ short AsH[128*64], BsH[BN*64];
    __shared__ short AsL[SPLIT ? 128*64 : 8], BsL[SPLIT ? BN*64 : 8];
    const int tid = threadIdx.x, lane = tid & 63, w = tid >> 6;
    const int m0 = blockIdx.y*128, n0 = blockIdx.x*BN;
    const int wm = (BN == 128) ? (w>>1)*64 : w*16;
    const int wn = (BN == 128) ? (w&1)*64 : 0;
    f32x4 acc[MF][4] = {};
    for (int k0 = 0; k0 < K; k0 += 64) {
        __syncthreads();
        #pragma unroll
        for (int u = 0; u < 128*8/NT; ++u) {
            int s = u*NT + tid;
            int row = s >> 3, sc = ((s & 7)*16) ^ ((row & 7) << 4);
            GL2LDS((const char*)(Ah + (size_t)(m0+row)*K + k0) + sc, &AsH[(u*NT + w*64)*8]);
            if constexpr (SPLIT)
                GL2LDS((const char*)(Al + (size_t)(m0+row)*K + k0) + sc, &AsL[(u*NT + w*64)*8]);
        }
        #pragma unroll
        for (int u = 0; u < BN*8/NT; ++u) {
            int s = u*NT + tid;
            int row = s >> 3, sc = ((s & 7)*16) ^ ((row & 7) << 4);
            GL2LDS((const char*)(Bh + (size_t)(n0+row)*K + k0) + sc, &BsH[(u*NT + w*64)*8]);
            if constexpr (SPLIT)
                GL2LDS((const char*)(Bl + (size_t)(n0+row)*K + k0) + sc, &BsL[(u*NT + w*64)*8]);
        }
        asm volatile("s_waitcnt vmcnt(0)" ::: "memory");
        __syncthreads();
        #pragma unroll
        for (int ks = 0; ks < 2; ++ks) {
            const int kb = ks*64 + (lane >> 4)*16;
            bf16x8 aH[MF], bH[4], aL[MF], bL[4];
            #pragma unroll
            for (int f = 0; f < MF; ++f) {
                int row = wm + f*16 + (lane & 15);
                int off = row*128 + (kb ^ ((row & 7) << 4));
                aH[f] = *(const bf16x8*)((char*)AsH + off);
                if constexpr (SPLIT) aL[f] = *(const bf16x8*)((char*)AsL + off);
            }
            #pragma unroll
            for (int f = 0; f < 4; ++f) {
                int row = wn + f*16 + (lane & 15);
                int off = row*128 + (kb ^ ((row & 7) << 4));
                bH[f] = *(const bf16x8*)((char*)BsH + off);
                if constexpr (SPLIT) bL[f] = *(const bf16x8*)((char*)BsL + off);
            }
            #pragma unroll
            for (int mf = 0; mf < MF; ++mf)
            #pragma unroll
            for (int nf = 0; nf < 4; ++nf) {
                acc[mf][nf] = MFMA_BF16(aH[mf], bH[nf], acc[mf][nf]);
                if constexpr (SPLIT) {
                    acc[mf][nf] = MFMA_BF16(aH[mf], bL[nf], acc[mf][nf]);
                    acc[mf][nf] = MFMA_BF16(aL[mf], bH[nf], acc[mf][nf]);
                }
            }
        }
    }
    #pragma unroll
    for (int mf = 0; mf < MF; ++mf)
    #pragma unroll
    for (int nf = 0; nf < 4; ++nf)
    #pragma unroll
    for (int r = 0; r < 4; ++r) {
        int m = m0 + wm + mf*16 + ((lane>>4)<<2) + r;
        int n = n0 + wn + nf*16 + (lane&15);
        float v = acc[mf][nf][r] + bias[n];
        if (EPI == 0) {
            ((float*)out1)[(size_t)m*N + n] = v;
        } else if (EPI == 3) {
            ((short*)out1)[(size_t)m*N + n] = f2bf(fmaxf(v, 0.f));
        } else if (EPI == 4) {
            ((float*)out1)[(size_t)m*N + n] = v + res[(size_t)m*N + n];
        }
    }
}

// ---------------------------------------------------------------------------
// Merged QKV GEMM: one dispatch, grid (48, 32), 512 threads / 8 waves.
// region = blockIdx.x>>4: 0 -> Q (split), 1 -> K (split), 2 -> V (v^T out).
// ---------------------------------------------------------------------------
__global__ __launch_bounds__(512) void qkv_mfma(
    const short* __restrict__ xh, const short* __restrict__ xl,
    const short* __restrict__ wqh, const short* __restrict__ wql,
    const short* __restrict__ wkh, const short* __restrict__ wkl,
    const short* __restrict__ wvT,
    const float* __restrict__ bq, const float* __restrict__ bk,
    const float* __restrict__ bv,
    short* __restrict__ qhB, short* __restrict__ qlB,
    short* __restrict__ khB, short* __restrict__ klB,
    short* __restrict__ vTout)
{
    const int region = blockIdx.x >> 4;
    const int n0 = (blockIdx.x & 15)*64;
    const int m0 = blockIdx.y*128;
    const bool split = region < 2;
    const short* Bh = region==0 ? wqh : (region==1 ? wkh : wvT);
    const short* Bl = region==0 ? wql : wkl;
    const float* bias = region==0 ? bq : (region==1 ? bk : bv);
    const int K = HID_;
    __shared__ short AsH[128*64], AsL[128*64], BsH[64*64], BsL[64*64];
    const int tid = threadIdx.x, lane = tid & 63, w = tid >> 6;
    const int wm = w*16;
    f32x4 acc[4] = {};
    for (int k0 = 0; k0 < K; k0 += 64) {
        __syncthreads();
        #pragma unroll
        for (int u = 0; u < 2; ++u) {
            int s = u*512 + tid;
            int row = s >> 3, sc = ((s & 7)*16) ^ ((row & 7) << 4);
            GL2LDS((const char*)(xh + (size_t)(m0+row)*K + k0) + sc, &AsH[(u*512 + w*64)*8]);
            if (split)
                GL2LDS((const char*)(xl + (size_t)(m0+row)*K + k0) + sc, &AsL[(u*512 + w*64)*8]);
        }
        {
            int s = tid;
            int row = s >> 3, sc = ((s & 7)*16) ^ ((row & 7) << 4);
            GL2LDS((const char*)(Bh + (size_t)(n0+row)*K + k0) + sc, &BsH[(w*64)*8]);
            if (split)
                GL2LDS((const char*)(Bl + (size_t)(n0+row)*K + k0) + sc, &BsL[(w*64)*8]);
        }
        asm volatile("s_waitcnt vmcnt(0)" ::: "memory");
        __syncthreads();
        #pragma unroll
        for (int ks = 0; ks < 2; ++ks) {
            const int kb = ks*64 + (lane >> 4)*16;
            bf16x8 aH, aL, bH[4], bL[4];
            {
                int row = wm + (lane & 15);
                int off = row*128 + (kb ^ ((row & 7) << 4));
                aH = *(const bf16x8*)((char*)AsH + off);
                if (split) aL = *(const bf16x8*)((char*)AsL + off);
            }
            #pragma unroll
            for (int f = 0; f < 4; ++f) {
                int row = f*16 + (lane & 15);
                int off = row*128 + (kb ^ ((row & 7) << 4));
                bH[f] = *(const bf16x8*)((char*)BsH + off);
                if (split) bL[f] = *(const bf16x8*)((char*)BsL + off);
            }
            #pragma unroll
            for (int nf = 0; nf < 4; ++nf) {
                acc[nf] = MFMA_BF16(aH, bH[nf], acc[nf]);
                if (split) {
                    acc[nf] = MFMA_BF16(aH, bL[nf], acc[nf]);
                    acc[nf] = MFMA_BF16(aL, bH[nf], acc[nf]);
                }
            }
        }
    }
    short* outH = region==0 ? qhB : khB;
    short* outL = region==0 ? qlB : klB;
    #pragma unroll
    for (int nf = 0; nf < 4; ++nf)
    #pragma unroll
    for (int r = 0; r < 4; ++r) {
        int m = m0 + wm + ((lane>>4)<<2) + r;
        int n = n0 + nf*16 + (lane&15);
        float v = acc[nf][r] + bias[n];
        int bb = m >> 10, ii = m & (S_-1), hh = n >> 6, dd = n & (DH_-1);
        if (region < 2) {
            size_t idx = (((size_t)bb*H_ + hh)*S_ + ii)*DH_ + dd;
            short hv = f2bf(v);
            outH[idx] = hv;
            outL[idx] = f2bf(v - bf2f(hv));
        } else {
            size_t idx = (((size_t)bb*H_ + hh)*DH_ + dd)*S_ + ii;
            vTout[idx] = f2bf(v);
        }
    }
}

// ---------------------------------------------------------------------------
// logits = QK^T + gather(R),  R = q @ relk[0..256]^T  (split-bf16 MFMA)
// 64-row i-blocks x 512 threads (8 waves): HALF the barrier phases of the
// 32-row version (the kernel is barrier-chain-bound, not occupancy-bound).
// Wave w -> (i-half = w>>2, j-frag = w&3); stats partials at 32-row
// granularity (2 per block) so colstats is unchanged.
// ---------------------------------------------------------------------------
__global__ __launch_bounds__(512) void qk_rel_kernel(
    const short* __restrict__ qh, const short* __restrict__ ql,
    const short* __restrict__ kh, const short* __restrict__ kl,
    const short* __restrict__ rkh, const short* __restrict__ rkl,
    float* __restrict__ Wt, float* __restrict__ pmP, float* __restrict__ psP)
{
    const int bid = blockIdx.x;
    const int bh = bid & 63, ib = bid >> 6;      // ib 0..15
    const int i0 = ib*64;
    const int tid = threadIdx.x, lane = tid & 63, w = tid >> 6;
    __shared__ short Qh[64*64], Ql[64*64];
    __shared__ short Kh[64*64], Kl[64*64];
    __shared__ short Rl[64*273];
    {
        int row = tid >> 3;
        int sc = ((tid & 7)*16) ^ ((row & 7) << 4);
        GL2LDS((const char*)(qh + ((size_t)bh*S_ + i0 + row)*DH_) + sc, &Qh[(w*64)*8]);
        GL2LDS((const char*)(ql + ((size_t)bh*S_ + i0 + row)*DH_) + sc, &Ql[(w*64)*8]);
    }
    asm volatile("s_waitcnt vmcnt(0)" ::: "memory");
    __syncthreads();
    // R phase: R = q @ relk^T for 64 rows x 272 offsets, 8 waves over nf
    for (int nf = w; nf < 17; nf += 8) {
        f32x4 racc[4] = {};
        #pragma unroll
        for (int ks = 0; ks < 2; ++ks) {
            const size_t ro = (size_t)(nf*16 + (lane&15))*DH_ + ks*32 + (lane>>4)*8;
            bf16x8 bHf = *(const bf16x8*)(rkh + ro);
            bf16x8 bLf = *(const bf16x8*)(rkl + ro);
            const int kb = ks*64 + (lane >> 4)*16;
            #pragma unroll
            for (int mf = 0; mf < 4; ++mf) {
                int row = mf*16 + (lane & 15);
                int off = row*128 + (kb ^ ((row & 7) << 4));
                bf16x8 A  = *(const bf16x8*)((char*)Qh + off);
                bf16x8 AL = *(const bf16x8*)((char*)Ql + off);
                racc[mf] = MFMA_BF16(A,  bHf, racc[mf]);
                racc[mf] = MFMA_BF16(A,  bLf, racc[mf]);
                racc[mf] = MFMA_BF16(AL, bHf, racc[mf]);
            }
        }
        #pragma unroll
        for (int mf = 0; mf < 4; ++mf)
        #pragma unroll
        for (int r = 0; r < 4; ++r)
            Rl[(mf*16 + ((lane>>4)<<2) + r)*273 + nf*16 + (lane&15)] = f2bf(racc[mf][r]);
    }
    const int ilim = i0 + 63;
    const int jf = w & 3, ih = w >> 2;           // j-frag, i-half
    for (int j0 = 0; j0 <= ilim; j0 += 64) {
        __syncthreads();
        {
            int row = tid >> 3;
            int sc = ((tid & 7)*16) ^ ((row & 7) << 4);
            GL2LDS((const char*)(kh + ((size_t)bh*S_ + j0 + row)*DH_) + sc, &Kh[(w*64)*8]);
            GL2LDS((const char*)(kl + ((size_t)bh*S_ + j0 + row)*DH_) + sc, &Kl[(w*64)*8]);
        }
        asm volatile("s_waitcnt vmcnt(0)" ::: "memory");
        __syncthreads();
        f32x4 acc[2] = {};
        #pragma unroll
        for (int ks = 0; ks < 2; ++ks) {
            const int kb = ks*64 + (lane >> 4)*16;
            int rowB = jf*16 + (lane & 15);
            int offB = rowB*128 + (kb ^ ((rowB & 7) << 4));
            bf16x8 bHf = *(const bf16x8*)((char*)Kh + offB);
            bf16x8 bLf = *(const bf16x8*)((char*)Kl + offB);
            #pragma unroll
            for (int mf = 0; mf < 2; ++mf) {
                int row = (ih*2 + mf)*16 + (lane & 15);
                int off = row*128 + (kb ^ ((row & 7) << 4));
                bf16x8 A  = *(const bf16x8*)((char*)Qh + off);
                bf16x8 AL = *(const bf16x8*)((char*)Ql + off);
                acc[mf] = MFMA_BF16(A,  bHf, acc[mf]);
                acc[mf] = MFMA_BF16(A,  bLf, acc[mf]);
                acc[mf] = MFMA_BF16(AL, bHf, acc[mf]);
            }
        }
        const int j = j0 + jf*16 + (lane & 15);
        float lreg[2][4];
        #pragma unroll
        for (int mf = 0; mf < 2; ++mf)
        #pragma unroll
        for (int r = 0; r < 4; ++r) {
            int i = i0 + (ih*2 + mf)*16 + ((lane>>4)<<2) + r;
            int o = j - i + 256;
            o = o < 0 ? 0 : (o > 272 ? 272 : o);
            float l = acc[mf][r] + bf2f(Rl[(i - i0)*273 + o]);
            Wt[((size_t)bh*S_ + i)*S_ + j] = l;
            lreg[mf][r] = (i >= j) ? l : -INFINITY;
        }
        float pm = -INFINITY;
        #pragma unroll
        for (int mf = 0; mf < 2; ++mf)
        #pragma unroll
        for (int r = 0; r < 4; ++r) pm = fmaxf(pm, lreg[mf][r]);
        float ps = 0.f;
        #pragma unroll
        for (int mf = 0; mf < 2; ++mf)
        #pragma unroll
        for (int r = 0; r < 4; ++r)
            if (lreg[mf][r] > -INFINITY) ps += __expf(lreg[mf][r] - pm);
        #pragma unroll
        for (int d = 16; d <= 32; d <<= 1) {
            float om = __shfl_xor(pm, d, 64);
            float os = __shfl_xor(ps, d, 64);
            float nm = fmaxf(pm, om);
            float pa = (pm > -INFINITY) ? ps*__expf(pm - nm) : 0.f;
            float pb = (om > -INFINITY) ? os*__expf(om - nm) : 0.f;
            pm = nm; ps = pa + pb;
        }
        if ((lane >> 4) == 0) {
            size_t sidx = ((size_t)bh*32 + ib*2 + ih)*S_ + j;
            pmP[sidx] = pm;
            psP[sidx] = ps;
        }
    }
}

// ---------------------------------------------------------------------------
// Combine the 32 per-32-row partials into per-column M and 1/D.
// ---------------------------------------------------------------------------
__global__ __launch_bounds__(256) void colstats_kernel(
    const float* __restrict__ pmP, const float* __restrict__ psP,
    float* __restrict__ Mcol, float* __restrict__ Dinv)
{
    const int bh = blockIdx.y;
    const int j = blockIdx.x*256 + threadIdx.x;
    const int it0 = j >> 5;
    float M = -INFINITY;
    for (int it = it0; it < 32; ++it)
        M = fmaxf(M, pmP[((size_t)bh*32 + it)*S_ + j]);
    float D = 0.f;
    for (int it = it0; it < 32; ++it) {
        float pm = pmP[((size_t)bh*32 + it)*S_ + j];
        if (pm > -INFINITY)
            D += psP[((size_t)bh*32 + it)*S_ + j] * __expf(pm - M);
    }
    Mcol[(size_t)bh*S_ + j] = M;
    Dinv[(size_t)bh*S_ + j] = 1.f / D;
}

// ---------------------------------------------------------------------------
// Fused normalize + PV + rel-vals band GEMM + upper-triangle zero fill.
// 64-row i-blocks, 512 threads / 8 waves, grid 1024 (bh = bid&63, iblk=bid>>6).
// ---------------------------------------------------------------------------
__global__ __launch_bounds__(512) void pv_norm_kernel(
    float* __restrict__ Wt, const short* __restrict__ vt,
    const float* __restrict__ Mcol, const float* __restrict__ Dinv,
    const short* __restrict__ relvT, short* __restrict__ attnctx)
{
    const int bid = blockIdx.x;
    const int bh = bid & 63, iblk = bid >> 6;
    const int i0 = iblk*64;
    const int b = bh >> 4, h = bh & (H_-1);
    const int tid = threadIdx.x, lane = tid & 63, w = tid >> 6;   // w 0..7
    __shared__ __align__(16) char smem[53248];
    short* Vs   = (short*)smem;              // [64][64] bf16, swizzled (8 KB)
    short* Ws   = (short*)(smem + 8192);     // [64][64] bf16, swizzled (8 KB)
    short* band = (short*)(smem + 16384);    // [64][288] bf16 (36 KB)
    float* Wb = Wt + (size_t)bh*S_*S_;
    const int cg = (tid & 15)*4;             // 4-column group per thread
    const int rq = tid >> 4;                 // 0..31; rows rq and rq+32
    #pragma unroll
    for (int u = 0; u < 5; ++u) {
        int s = u*512 + tid;
        if (s < 2304) ((int4*)band)[s] = make_int4(0,0,0,0);
    }
    float rowsum[2] = {}, bandsum[2] = {};
    f32x4 acc[2] = {};
    const int if_ = w & 3, df0 = (w >> 2)*2; // 8 waves = 4 i-frags x 2 d-pairs
    const int vr = tid >> 3, vc = (tid & 7)*8;
    const size_t vbase = (size_t)bh*DH_*S_;
    float4 Lreg[2];
    #pragma unroll
    for (int u = 0; u < 2; ++u)
        Lreg[u] = *(const float4*)(Wb + (size_t)(i0 + u*32 + rq)*S_ + cg);
    float4 Mj = *(const float4*)(Mcol + (size_t)bh*S_ + cg);
    float4 Dj = *(const float4*)(Dinv + (size_t)bh*S_ + cg);
    __syncthreads();
    for (int j0 = 0; j0 <= i0; j0 += 64) {
        bf16x8 v0 = *(const bf16x8*)(vt + vbase + (size_t)vr*S_ + j0 + vc);
        float wv[2][4];
        #pragma unroll
        for (int u = 0; u < 2; ++u) {
            int ig = i0 + u*32 + rq;
            wv[u][0] = (ig >= j0+cg+0) ? __expf(Lreg[u].x - Mj.x)*Dj.x : 0.f;
            wv[u][1] = (ig >= j0+cg+1) ? __expf(Lreg[u].y - Mj.y)*Dj.y : 0.f;
            wv[u][2] = (ig >= j0+cg+2) ? __expf(Lreg[u].z - Mj.z)*Dj.z : 0.f;
            wv[u][3] = (ig >= j0+cg+3) ? __expf(Lreg[u].w - Mj.w)*Dj.w : 0.f;
        }
        #pragma unroll
        for (int u = 0; u < 2; ++u) {
            float4 w4; w4.x=wv[u][0]; w4.y=wv[u][1]; w4.z=wv[u][2]; w4.w=wv[u][3];
            *(float4*)(Wb + (size_t)(i0 + u*32 + rq)*S_ + j0 + cg) = w4;
        }
        float4 Lnext[2] = {};
        float4 Mn = Mj, Dn = Dj;
        const int j1 = j0 + 64;
        if (j1 <= i0) {
            #pragma unroll
            for (int u = 0; u < 2; ++u)
                Lnext[u] = *(const float4*)(Wb + (size_t)(i0 + u*32 + rq)*S_ + j1 + cg);
            Mn = *(const float4*)(Mcol + (size_t)bh*S_ + j1 + cg);
            Dn = *(const float4*)(Dinv + (size_t)bh*S_ + j1 + cg);
        }
        *(bf16x8*)((char*)Vs + vr*128 + ((vc*2) ^ ((vr & 7) << 4))) = v0;
        #pragma unroll
        for (int u = 0; u < 2; ++u) {
            int r = u*32 + rq;
            int ig = i0 + r;
            short4 wb4; wb4.x=f2bf(wv[u][0]); wb4.y=f2bf(wv[u][1]);
            wb4.z=f2bf(wv[u][2]); wb4.w=f2bf(wv[u][3]);
            *(short4*)((char*)Ws + r*128 + ((cg*2) ^ ((r & 7) << 4))) = wb4;
            rowsum[u] += wv[u][0] + wv[u][1] + wv[u][2] + wv[u][3];
            const int obase = j0 + cg - ig + 256;
            #pragma unroll
            for (int c = 0; c < 4; ++c) {
                int o = obase + c;
                if (o >= 1 && o <= 256) {
                    band[r*288 + o] = f2bf(wv[u][c]);
                    bandsum[u] += wv[u][c];
                }
            }
        }
        __syncthreads();
        const int kq16 = (lane >> 4)*16;
        #pragma unroll
        for (int ks = 0; ks < 2; ++ks) {
            bf16x8 bw;
            {
                int row = if_*16 + (lane & 15);
                bw = *(const bf16x8*)((char*)Ws + row*128 +
                      ((ks*64 + kq16) ^ ((row & 7) << 4)));
            }
            #pragma unroll
            for (int dfi = 0; dfi < 2; ++dfi) {
                int row = (df0 + dfi)*16 + (lane & 15);
                bf16x8 av = *(const bf16x8*)((char*)Vs + row*128 +
                      ((ks*64 + kq16) ^ ((row & 7) << 4)));
                acc[dfi] = MFMA_BF16(av, bw, acc[dfi]);
            }
        }
        __syncthreads();
        #pragma unroll
        for (int u = 0; u < 2; ++u) Lreg[u] = Lnext[u];
        Mj = Mn; Dj = Dn;
    }
    #pragma unroll
    for (int u = 0; u < 2; ++u) {
        #pragma unroll
        for (int m = 1; m <= 8; m <<= 1) {
            rowsum[u]  += __shfl_xor(rowsum[u],  m, 64);
            bandsum[u] += __shfl_xor(bandsum[u], m, 64);
        }
    }
    if ((tid & 15) == 0) {
        #pragma unroll
        for (int u = 0; u < 2; ++u)
            band[(u*32 + rq)*288] = f2bf(rowsum[u] - bandsum[u]);
    }
    __syncthreads();
    f32x4 acc2[2] = {};
    const int mf_ = w & 3, nf0 = (w >> 2)*2;
    const int kq = (lane >> 4)*8;
    #pragma unroll
    for (int ks = 0; ks < 9; ++ks) {
        bf16x8 a = *(const bf16x8*)&band[(mf_*16 + (lane & 15))*288 + ks*32 + kq];
        #pragma unroll
        for (int nfi = 0; nfi < 2; ++nfi) {
            bf16x8 bb = *(const bf16x8*)&relvT[(size_t)((nf0+nfi)*16 + (lane & 15))*288 + ks*32 + kq];
            acc2[nfi] = MFMA_BF16(a, bb, acc2[nfi]);
        }
    }
    __syncthreads();
    float* Os = (float*)band;                // [64][68] fp32 (17408 B, fits)
    #pragma unroll
    for (int dfi = 0; dfi < 2; ++dfi)
    #pragma unroll
    for (int r = 0; r < 4; ++r) {
        int d  = (df0 + dfi)*16 + ((lane >> 4) << 2) + r;
        int il = if_*16 + (lane & 15);
        Os[il*68 + d] = acc[dfi][r];
    }
    __syncthreads();
    #pragma unroll
    for (int nfi = 0; nfi < 2; ++nfi)
    #pragma unroll
    for (int rr = 0; rr < 4; ++rr) {
        int ii = mf_*16 + ((lane >> 4) << 2) + rr;
        int d  = (nf0 + nfi)*16 + (lane & 15);
        Os[ii*68 + d] += acc2[nfi][rr];
    }
    __syncthreads();
    {
        int row = tid >> 3, q8 = (tid & 7)*8;
        short* dst = attnctx + ((size_t)b*S_ + i0 + row)*HID_ + h*DH_ + q8;
        short tmp[8];
        #pragma unroll
        for (int e = 0; e < 8; ++e) tmp[e] = f2bf(Os[row*68 + q8 + e]);
        *(int4*)(dst) = *(int4*)(tmp);
    }
    {
        const int c0 = i0 + 64;
        if (c0 < S_) {
            float4 z; z.x = 0.f; z.y = 0.f; z.z = 0.f; z.w = 0.f;
            const int r = tid >> 3;
            float* rowp = Wb + (size_t)(i0 + r)*S_;
            for (int c = c0 + (tid & 7)*4; c < S_; c += 32)
                *(float4*)(rowp + c) = z;
        }
    }
}

// ---------------------------------------------------------------------------
// ctx = LayerNorm(y + x)*g + b + x ; also bf16 copy for FFN
// ---------------------------------------------------------------------------
__global__ __launch_bounds__(256) void ln_kernel(
    const float* __restrict__ y, const float* __restrict__ x,
    const float* __restrict__ g, const float* __restrict__ bta,
    float* __restrict__ ctx, short* __restrict__ ctxb)
{
    const int row = blockIdx.x;
    const int tid = threadIdx.x;
    float t[4], xv[4];
    #pragma unroll
    for (int u = 0; u < 4; ++u) {
        int c = tid + u*256;
        xv[u] = x[(size_t)row*HID_ + c];
        t[u]  = y[(size_t)row*HID_ + c] + xv[u];
    }
    __shared__ float red[4];
    float s = t[0] + t[1] + t[2] + t[3];
    #pragma unroll
    for (int o = 32; o > 0; o >>= 1) s += __shfl_down(s, o, 64);
    if ((tid & 63) == 0) red[tid >> 6] = s;
    __syncthreads();
    const float mean = (red[0]+red[1]+red[2]+red[3]) * (1.f/1024.f);
    float vsum = 0.f;
    #pragma unroll
    for (int u = 0; u < 4; ++u) { float dd = t[u]-mean; vsum += dd*dd; }
    __syncthreads();
    #pragma unroll
    for (int o = 32; o > 0; o >>= 1) vsum += __shfl_down(vsum, o, 64);
    if ((tid & 63) == 0) red[tid >> 6] = vsum;
    __syncthreads();
    const float var = (red[0]+red[1]+red[2]+red[3]) * (1.f/1024.f);
    const float rstd = rsqrtf(var + 1e-5f);
    #pragma unroll
    for (int u = 0; u < 4; ++u) {
        int c = tid + u*256;
        float cv = (t[u]-mean)*rstd*g[c] + bta[c] + xv[u];
        ctx[(size_t)row*HID_ + c] = cv;
        ctxb[(size_t)row*HID_ + c] = f2bf(cv);
    }
}

// ---------------------------------------------------------------------------
extern "C" void kernel_launch(void* const* d_in, const int* in_sizes, int n_in,
                              void* d_out, int out_size, void* d_ws, size_t ws_size,
                              hipStream_t stream)
{
    const float* x    = (const float*)d_in[0];
    const float* Wq   = (const float*)d_in[1];
    const float* bq   = (const float*)d_in[2];
    const float* Wk   = (const float*)d_in[3];
    const float* bk   = (const float*)d_in[4];
    const float* Wv   = (const float*)d_in[5];
    const float* bv   = (const float*)d_in[6];
    const float* relk = (const float*)d_in[7];
    const float* relv = (const float*)d_in[8];
    const float* Wo   = (const float*)d_in[9];
    const float* bo   = (const float*)d_in[10];
    const float* lng  = (const float*)d_in[11];
    const float* lnb  = (const float*)d_in[12];
    const float* W1   = (const float*)d_in[13];
    const float* b1   = (const float*)d_in[14];
    const float* W2   = (const float*)d_in[15];
    const float* b2   = (const float*)d_in[16];

    float* contexts = (float*)d_out;                       // (B,S,HID) fp32
    float* Wt = contexts + (size_t)B_*S_*HID_;             // weights (B,H,S,S) fp32

    char* ws = (char*)d_ws;
    short* xh   = (short*)(ws + 0);            // 8 MB  (region reused as y fp32)
    short* xl   = (short*)(ws + 8388608);
    float* y    = (float*)(ws + 0);            // 16 MB (after QKV done)
    short* wqh  = (short*)(ws + 16777216);
    short* wql  = (short*)(ws + 18874368);
    short* wkh  = (short*)(ws + 20971520);
    short* wkl  = (short*)(ws + 23068672);
    short* wvT  = (short*)(ws + 25165824);
    short* woT  = (short*)(ws + 27262976);
    short* w1T  = (short*)(ws + 29360128);
    short* w2T  = (short*)(ws + 37748736);
    short* rkh  = (short*)(ws + 46137344);
    short* rkl  = (short*)(ws + 46202880);
    short* qhB  = (short*)(ws + 46268416);     // q/k hi/lo (reused as h1)
    short* qlB  = (short*)(ws + 54657024);
    short* khB  = (short*)(ws + 63045632);
    short* klB  = (short*)(ws + 71434240);
    short* h1   = (short*)(ws + 46268416);     // 32 MB, overlaps dead q/k
    short* vT   = (short*)(ws + 79822848);     // 8 MB
    short* attn = (short*)(ws + 88211456);     // 8 MB
    float* ctx  = (float*)(ws + 96600064);     // 16 MB
    short* ctxb = (short*)(ws + 113377280);    // 8 MB
    float* pmP  = (float*)(ws + 121765888);    // 8 MB partial max
    float* psP  = (float*)(ws + 130154496);    // 8 MB partial sumexp
    float* Mcol = (float*)(ws + 138543104);    // 256 KB
    float* Dinv = (float*)(ws + 138805248);    // 256 KB
    short* relvT= (short*)(ws + 139067392);    // 36 KB [64][288] bf16

    const int M = B_*S_;
    dim3 blk(256), blk512(512);

    convert_all<<<7257, blk, 0, stream>>>(x, Wq, Wk, Wv, Wo, W1, W2, relk, relv,
                                          xh, xl, wqh, wql, wkh, wkl, wvT, woT,
                                          w1T, w2T, rkh, rkl, relvT);

    qkv_mfma<<<dim3(48,32), blk512, 0, stream>>>(xh, xl, wqh, wql, wkh, wkl, wvT,
                                                 bq, bk, bv, qhB, qlB, khB, klB, vT);

    qk_rel_kernel<<<1024, blk512, 0, stream>>>(qhB, qlB, khB, klB, rkh, rkl, Wt, pmP, psP);
    colstats_kernel<<<dim3(4,64), blk, 0, stream>>>(pmP, psP, Mcol, Dinv);
    pv_norm_kernel<<<1024, blk512, 0, stream>>>(Wt, vT, Mcol, Dinv, relvT, attn);

    gemm_mfma<0,false,64><<<dim3(16,32), blk512, 0, stream>>>(attn, nullptr, woT, nullptr, bo, nullptr, y, nullptr, M, HID_, HID_);
    ln_kernel<<<M, blk, 0, stream>>>(y, x, lng, lnb, ctx, ctxb);
    gemm_mfma<3,false,128><<<dim3(32,32), blk, 0, stream>>>(ctxb, nullptr, w1T, nullptr, b1, nullptr, h1, nullptr, M, FF_, HID_);
    gemm_mfma<4,false,64><<<dim3(16,32), blk512, 0, stream>>>(h1, nullptr, w2T, nullptr, b2, ctx, contexts, nullptr, M, HID_, FF_);
}